// Round 1
// baseline (290.925 us; speedup 1.0000x reference)
//
#include <hip/hip_runtime.h>

typedef unsigned int uint32;
typedef unsigned long long uint64;

#define BLOCK 256
#define IPT 16
#define CHUNK (BLOCK * IPT)   // 4096 rows per block
#define SCORE_THR 0.35f

// ---------------- Kernel 1: per-block mask counts ----------------
__global__ void count_kernel(const float* __restrict__ det,
                             uint32* __restrict__ c0, uint32* __restrict__ c1,
                             int R) {
    int tid = threadIdx.x;
    long long base = (long long)blockIdx.x * CHUNK;
    uint32 cnt0 = 0, cnt1 = 0;
    for (int i = 0; i < IPT; ++i) {
        long long row = base + (long long)i * BLOCK + tid;
        if (row < R) {
            const float* p = det + row * 6;
            float c = p[0];
            float s = p[5];
            bool m1 = (s >= SCORE_THR);
            bool m0 = m1 && (c == 0.0f);
            cnt1 += m1 ? 1u : 0u;
            cnt0 += m0 ? 1u : 0u;
        }
    }
    // wave reduction (64 lanes)
    for (int off = 32; off > 0; off >>= 1) {
        cnt0 += __shfl_down(cnt0, off, 64);
        cnt1 += __shfl_down(cnt1, off, 64);
    }
    __shared__ uint32 r0[BLOCK / 64], r1[BLOCK / 64];
    int wave = tid >> 6, lane = tid & 63;
    if (lane == 0) { r0[wave] = cnt0; r1[wave] = cnt1; }
    __syncthreads();
    if (tid == 0) {
        uint32 t0 = 0, t1 = 0;
        for (int w = 0; w < BLOCK / 64; ++w) { t0 += r0[w]; t1 += r1[w]; }
        c0[blockIdx.x] = t0;
        c1[blockIdx.x] = t1;
    }
}

// ---------------- Kernel 2: exclusive scan of block counts ----------------
__global__ void scan_kernel(const uint32* __restrict__ c0, const uint32* __restrict__ c1,
                            uint32* __restrict__ o0, uint32* __restrict__ o1,
                            uint32* __restrict__ totals, float* __restrict__ out_n,
                            int nb) {
    __shared__ uint32 s0[1024], s1[1024];
    int t = threadIdx.x;
    uint32 carry0 = 0, carry1 = 0;
    for (int basei = 0; basei < nb; basei += 1024) {
        int i = basei + t;
        uint32 v0 = (i < nb) ? c0[i] : 0u;
        uint32 v1 = (i < nb) ? c1[i] : 0u;
        s0[t] = v0; s1[t] = v1;
        __syncthreads();
        for (int d = 1; d < 1024; d <<= 1) {
            uint32 a0 = (t >= d) ? s0[t - d] : 0u;
            uint32 a1 = (t >= d) ? s1[t - d] : 0u;
            __syncthreads();
            s0[t] += a0; s1[t] += a1;
            __syncthreads();
        }
        if (i < nb) {
            o0[i] = carry0 + s0[t] - v0;   // exclusive
            o1[i] = carry1 + s1[t] - v1;
        }
        uint32 tot0 = carry0 + s0[1023];
        uint32 tot1 = carry1 + s1[1023];
        __syncthreads();
        carry0 = tot0; carry1 = tot1;
    }
    if (t == 0) {
        totals[0] = carry0;
        totals[1] = carry1;
        out_n[0] = (float)carry0;   // n
        out_n[1] = (float)carry1;   // n_full
    }
}

// ---------------- Kernel 3: stable scatter ----------------
__global__ void scatter_kernel(const float* __restrict__ det,
                               float* __restrict__ rois, float* __restrict__ roisf,
                               const uint32* __restrict__ o0, const uint32* __restrict__ o1,
                               int R) {
    __shared__ uint32 wc0[BLOCK / 64], wc1[BLOCK / 64];
    __shared__ uint32 run0, run1;
    int tid = threadIdx.x;
    int wave = tid >> 6, lane = tid & 63;
    if (tid == 0) { run0 = o0[blockIdx.x]; run1 = o1[blockIdx.x]; }
    __syncthreads();
    long long base = (long long)blockIdx.x * CHUNK;
    for (int i = 0; i < IPT; ++i) {
        long long row = base + (long long)i * BLOCK + tid;
        bool m0 = false, m1 = false;
        float d0 = 0, d1 = 0, d2 = 0, d3 = 0, d4 = 0, d5 = 0;
        if (row < R) {
            const float* p = det + row * 6;
            d0 = p[0]; d1 = p[1]; d2 = p[2]; d3 = p[3]; d4 = p[4]; d5 = p[5];
            m1 = (d5 >= SCORE_THR);
            m0 = m1 && (d0 == 0.0f);
        }
        uint64 b0 = __ballot(m0);
        uint64 b1 = __ballot(m1);
        if (lane == 0) { wc0[wave] = (uint32)__popcll(b0); wc1[wave] = (uint32)__popcll(b1); }
        __syncthreads();
        uint32 wp0 = 0, wp1 = 0;
        for (int w = 0; w < wave; ++w) { wp0 += wc0[w]; wp1 += wc1[w]; }
        uint64 lt = (lane == 0) ? 0ull : ((1ull << lane) - 1ull);
        if (m0) {
            uint32 pos = run0 + wp0 + (uint32)__popcll(b0 & lt);
            float* q = rois + (long long)pos * 5;
            q[0] = 0.0f; q[1] = d1; q[2] = d2; q[3] = d3; q[4] = d4;
        }
        if (m1) {
            uint32 pos = run1 + wp1 + (uint32)__popcll(b1 & lt);
            float* q = roisf + (long long)pos * 6;
            q[0] = d0; q[1] = d1; q[2] = d2; q[3] = d3; q[4] = d4; q[5] = d5;
        }
        __syncthreads();
        if (tid == 0) {
            uint32 t0 = 0, t1 = 0;
            for (int w = 0; w < BLOCK / 64; ++w) { t0 += wc0[w]; t1 += wc1[w]; }
            run0 += t0; run1 += t1;
        }
        __syncthreads();
    }
}

// ---------------- Kernel 4: zero-fill tails ----------------
__global__ void zero_kernel(float* __restrict__ rois, float* __restrict__ roisf,
                            const uint32* __restrict__ totals, long long R) {
    long long n0 = totals[0], n1 = totals[1];
    long long z0 = R * 5 - n0 * 5;       // floats to zero in rois
    long long z1 = R * 6 - n1 * 6;       // floats to zero in rois_full
    long long total = z0 + z1;
    long long idx = (long long)blockIdx.x * blockDim.x + threadIdx.x;
    long long stride = (long long)gridDim.x * blockDim.x;
    float* base0 = rois + n0 * 5;
    float* base1 = roisf + n1 * 6;
    for (long long k = idx; k < total; k += stride) {
        if (k < z0) base0[k] = 0.0f;
        else        base1[k - z0] = 0.0f;
    }
}

extern "C" void kernel_launch(void* const* d_in, const int* in_sizes, int n_in,
                              void* d_out, int out_size, void* d_ws, size_t ws_size,
                              hipStream_t stream) {
    const float* det = (const float*)d_in[0];
    float* out = (float*)d_out;
    int R = in_sizes[0] / 6;
    int NB = (R + CHUNK - 1) / CHUNK;

    uint32* ws = (uint32*)d_ws;
    uint32* c0 = ws;
    uint32* c1 = ws + NB;
    uint32* o0 = ws + 2 * NB;
    uint32* o1 = ws + 3 * NB;
    uint32* totals = ws + 4 * NB;

    float* rois  = out;                          // (R,5)
    float* roisf = out + (long long)R * 5;       // (R,6)
    float* nout  = out + (long long)R * 11;      // n, n_full

    count_kernel<<<NB, BLOCK, 0, stream>>>(det, c0, c1, R);
    scan_kernel<<<1, 1024, 0, stream>>>(c0, c1, o0, o1, totals, nout, NB);
    scatter_kernel<<<NB, BLOCK, 0, stream>>>(det, rois, roisf, o0, o1, R);
    zero_kernel<<<2048, BLOCK, 0, stream>>>(rois, roisf, totals, (long long)R);
}